// Round 2
// baseline (648.736 us; speedup 1.0000x reference)
//
#include <hip/hip_runtime.h>

// out = swish(mw * swish(GN_{G=32}(x @ W^T + bias)))
// B=8192, K=4096, C=4096. ALL inputs/outputs are FP32 (reference dtypes).
// Round-1 NaN root cause: inputs were read as bf16. Fix: fp32 I/O, with an
// explicit fp32->bf16 convert pre-pass into d_ws feeding the m97-structure
// bf16 MFMA GEMM. Group size C/G = 128 == BN -> GroupNorm fully block-local.

typedef short bf16x8 __attribute__((ext_vector_type(8)));
typedef unsigned short u16x8 __attribute__((ext_vector_type(8)));
typedef unsigned short u16x4 __attribute__((ext_vector_type(4)));
typedef float fx4 __attribute__((ext_vector_type(4)));

__device__ __forceinline__ unsigned short f2bf(float f) {
    union { float f; unsigned u; } v; v.f = f;
    unsigned r = v.u + 0x7FFFu + ((v.u >> 16) & 1u);   // RTNE
    return (unsigned short)(r >> 16);
}

__device__ __forceinline__ void load_lds16(const void* g, void* l) {
    __builtin_amdgcn_global_load_lds(
        (const __attribute__((address_space(1))) void*)g,
        (__attribute__((address_space(3))) void*)l, 16, 0, 0);
}

// ---------------- fp32 -> bf16 convert pre-pass (8 elems/thread) ----------------
__global__ void __launch_bounds__(256)
cvt_f32_bf16(const float* __restrict__ src, unsigned short* __restrict__ dst, long long n) {
    long long i = ((long long)blockIdx.x * 256 + threadIdx.x) * 8;
    if (i >= n) return;
    float4 a = *(const float4*)(src + i);
    float4 b = *(const float4*)(src + i + 4);
    u16x8 o;
    o[0] = f2bf(a.x); o[1] = f2bf(a.y); o[2] = f2bf(a.z); o[3] = f2bf(a.w);
    o[4] = f2bf(b.x); o[5] = f2bf(b.y); o[6] = f2bf(b.z); o[7] = f2bf(b.w);
    *(u16x8*)(dst + i) = o;
}

// ---------------- shared epilogue: bias + GroupNorm + swish*mw*swish ----------------
__device__ __forceinline__ void
epilogue(fx4 (&acc)[4][4],
         const float* __restrict__ bias, const float* __restrict__ gnw,
         const float* __restrict__ gnb,  const float* __restrict__ mw,
         float* __restrict__ out, int m0, int n0,
         int wm, int wn, int lrow, int q,
         float (*redS)[128], float (*redQ)[128]) {
    constexpr int C = 4096;
    float bia[4], gw[4], gb[4], mwv[4];
    int cidx[4];
    #pragma unroll
    for (int nt = 0; nt < 4; nt++) {
        int c = n0 + wn * 64 + nt * 16 + lrow;
        cidx[nt] = c;
        bia[nt] = bias[c]; gw[nt] = gnw[c]; gb[nt] = gnb[c]; mwv[nt] = mw[c];
    }
    #pragma unroll
    for (int mt = 0; mt < 4; mt++)
        #pragma unroll
        for (int nt = 0; nt < 4; nt++)
            #pragma unroll
            for (int r = 0; r < 4; r++)
                acc[mt][nt][r] += bia[nt];

    // per-lane partials over this lane's 4 columns, for its 16 rows
    float s[4][4], ss[4][4];
    #pragma unroll
    for (int mt = 0; mt < 4; mt++)
        #pragma unroll
        for (int r = 0; r < 4; r++) {
            float a = 0.f, b = 0.f;
            #pragma unroll
            for (int nt = 0; nt < 4; nt++) {
                float v = acc[mt][nt][r];
                a += v; b += v * v;
            }
            s[mt][r] = a; ss[mt][r] = b;
        }
    // butterfly across the 16 lanes sharing q (covers the wave's 64 cols)
    #pragma unroll
    for (int off = 1; off < 16; off <<= 1)
        #pragma unroll
        for (int mt = 0; mt < 4; mt++)
            #pragma unroll
            for (int r = 0; r < 4; r++) {
                s[mt][r]  += __shfl_xor(s[mt][r],  off, 64);
                ss[mt][r] += __shfl_xor(ss[mt][r], off, 64);
            }
    // cross-wave (wn=0,1) exchange via LDS
    if (lrow == 0) {
        #pragma unroll
        for (int mt = 0; mt < 4; mt++)
            #pragma unroll
            for (int r = 0; r < 4; r++) {
                int row = wm * 64 + mt * 16 + q * 4 + r;
                redS[wn][row] = s[mt][r];
                redQ[wn][row] = ss[mt][r];
            }
    }
    __syncthreads();

    #pragma unroll
    for (int mt = 0; mt < 4; mt++)
        #pragma unroll
        for (int r = 0; r < 4; r++) {
            int row = wm * 64 + mt * 16 + q * 4 + r;
            float tot  = redS[0][row] + redS[1][row];
            float tq   = redQ[0][row] + redQ[1][row];
            float mean = tot * (1.0f / 128.0f);
            float var  = tq * (1.0f / 128.0f) - mean * mean;
            s[mt][r]  = mean;
            ss[mt][r] = rsqrtf(var + 1e-5f);
        }

    #pragma unroll
    for (int mt = 0; mt < 4; mt++)
        #pragma unroll
        for (int r = 0; r < 4; r++) {
            size_t row = (size_t)(m0 + wm * 64 + mt * 16 + q * 4 + r);
            #pragma unroll
            for (int nt = 0; nt < 4; nt++) {
                float h  = acc[mt][nt][r];
                float hn = (h - s[mt][r]) * ss[mt][r];
                hn = hn * gw[nt] + gb[nt];
                float x1 = hn / (1.0f + __expf(-hn));
                float x2 = x1 * mwv[nt];
                float y  = x2 / (1.0f + __expf(-x2));
                out[row * (size_t)C + cidx[nt]] = y;
            }
        }
}

// ---------------- fast path: bf16 operands from d_ws, global_load_lds staging ----------------
__global__ void __launch_bounds__(256)
gemm_bf16(const unsigned short* __restrict__ X,    // [8192,4096] bf16 (ws)
          const unsigned short* __restrict__ Wt,   // [4096,4096] bf16 (ws)
          const float* __restrict__ bias, const float* __restrict__ gnw,
          const float* __restrict__ gnb,  const float* __restrict__ mw,
          float* __restrict__ out)
{
    constexpr int K = 4096;
    __shared__ __align__(16) unsigned short As[128 * 32];
    __shared__ __align__(16) unsigned short Bs[128 * 32];
    __shared__ float redS[2][128];
    __shared__ float redQ[2][128];

    const int tid  = threadIdx.x;
    const int wave = tid >> 6;
    const int lane = tid & 63;
    const int wm = wave >> 1, wn = wave & 1;
    const int lrow = lane & 15;
    const int q    = lane >> 4;

    const int m0 = blockIdx.y * 128;
    const int n0 = blockIdx.x * 128;

    const int r0 = tid >> 2;
    const int kk = (tid & 3) * 8;
    const unsigned short* pA0 = X  + (size_t)(m0 + r0) * K + kk;
    const unsigned short* pA1 = X  + (size_t)(m0 + 64 + r0) * K + kk;
    const unsigned short* pB0 = Wt + (size_t)(n0 + r0) * K + kk;
    const unsigned short* pB1 = Wt + (size_t)(n0 + 64 + r0) * K + kk;
    unsigned short* ldsA0 = &As[wave * 512];
    unsigned short* ldsA1 = &As[2048 + wave * 512];
    unsigned short* ldsB0 = &Bs[wave * 512];
    unsigned short* ldsB1 = &Bs[2048 + wave * 512];

    fx4 acc[4][4];
    const fx4 zero = {0.f, 0.f, 0.f, 0.f};
    #pragma unroll
    for (int i = 0; i < 4; i++)
        #pragma unroll
        for (int j = 0; j < 4; j++) acc[i][j] = zero;

    for (int k0 = 0; k0 < K; k0 += 32) {
        load_lds16(pA0 + k0, ldsA0);
        load_lds16(pA1 + k0, ldsA1);
        load_lds16(pB0 + k0, ldsB0);
        load_lds16(pB1 + k0, ldsB1);
        __syncthreads();

        bf16x8 af[4], bfr[4];
        #pragma unroll
        for (int mt = 0; mt < 4; mt++)
            af[mt] = *(const bf16x8*)&As[(wm * 64 + mt * 16 + lrow) * 32 + q * 8];
        #pragma unroll
        for (int nt = 0; nt < 4; nt++)
            bfr[nt] = *(const bf16x8*)&Bs[(wn * 64 + nt * 16 + lrow) * 32 + q * 8];

        #pragma unroll
        for (int mt = 0; mt < 4; mt++)
            #pragma unroll
            for (int nt = 0; nt < 4; nt++)
                acc[mt][nt] = __builtin_amdgcn_mfma_f32_16x16x32_bf16(
                    af[mt], bfr[nt], acc[mt][nt], 0, 0, 0);
        __syncthreads();
    }

    epilogue(acc, bias, gnw, gnb, mw, out, m0, n0, wm, wn, lrow, q, redS, redQ);
}

// ---------------- fallback: fp32 inputs, convert during LDS staging ----------------
__global__ void __launch_bounds__(256)
gemm_f32cvt(const float* __restrict__ X, const float* __restrict__ Wt,
            const float* __restrict__ bias, const float* __restrict__ gnw,
            const float* __restrict__ gnb,  const float* __restrict__ mw,
            float* __restrict__ out)
{
    constexpr int K = 4096;
    __shared__ __align__(16) unsigned short As[128 * 32];
    __shared__ __align__(16) unsigned short Bs[128 * 32];
    __shared__ float redS[2][128];
    __shared__ float redQ[2][128];

    const int tid  = threadIdx.x;
    const int wave = tid >> 6;
    const int lane = tid & 63;
    const int wm = wave >> 1, wn = wave & 1;
    const int lrow = lane & 15;
    const int q    = lane >> 4;

    const int m0 = blockIdx.y * 128;
    const int n0 = blockIdx.x * 128;

    const int srow = tid >> 3;          // 0..31
    const int sk   = (tid & 7) * 4;     // 0,4,..,28

    fx4 acc[4][4];
    const fx4 zero = {0.f, 0.f, 0.f, 0.f};
    #pragma unroll
    for (int i = 0; i < 4; i++)
        #pragma unroll
        for (int j = 0; j < 4; j++) acc[i][j] = zero;

    for (int k0 = 0; k0 < K; k0 += 32) {
        #pragma unroll
        for (int j = 0; j < 4; j++) {
            int row = j * 32 + srow;
            float4 va = *(const float4*)(X  + (size_t)(m0 + row) * K + k0 + sk);
            float4 vb = *(const float4*)(Wt + (size_t)(n0 + row) * K + k0 + sk);
            u16x4 oa = { f2bf(va.x), f2bf(va.y), f2bf(va.z), f2bf(va.w) };
            u16x4 ob = { f2bf(vb.x), f2bf(vb.y), f2bf(vb.z), f2bf(vb.w) };
            *(u16x4*)&As[row * 32 + sk] = oa;
            *(u16x4*)&Bs[row * 32 + sk] = ob;
        }
        __syncthreads();

        bf16x8 af[4], bfr[4];
        #pragma unroll
        for (int mt = 0; mt < 4; mt++)
            af[mt] = *(const bf16x8*)&As[(wm * 64 + mt * 16 + lrow) * 32 + q * 8];
        #pragma unroll
        for (int nt = 0; nt < 4; nt++)
            bfr[nt] = *(const bf16x8*)&Bs[(wn * 64 + nt * 16 + lrow) * 32 + q * 8];

        #pragma unroll
        for (int mt = 0; mt < 4; mt++)
            #pragma unroll
            for (int nt = 0; nt < 4; nt++)
                acc[mt][nt] = __builtin_amdgcn_mfma_f32_16x16x32_bf16(
                    af[mt], bfr[nt], acc[mt][nt], 0, 0, 0);
        __syncthreads();
    }

    epilogue(acc, bias, gnw, gnb, mw, out, m0, n0, wm, wn, lrow, q, redS, redQ);
}

extern "C" void kernel_launch(void* const* d_in, const int* in_sizes, int n_in,
                              void* d_out, int out_size, void* d_ws, size_t ws_size,
                              hipStream_t stream) {
    (void)in_sizes; (void)n_in; (void)out_size;
    const float* X    = (const float*)d_in[0];   // [8192,4096]
    const float* Wt   = (const float*)d_in[1];   // [4096,4096]
    const float* bias = (const float*)d_in[2];
    const float* gnw  = (const float*)d_in[3];
    const float* gnb  = (const float*)d_in[4];
    const float* mw   = (const float*)d_in[5];
    float* out = (float*)d_out;

    const long long nX = 8192LL * 4096LL;   // 33554432
    const long long nW = 4096LL * 4096LL;   // 16777216
    const size_t need = (size_t)(nX + nW) * 2;

    dim3 grid(4096 / 128, 8192 / 128);

    if (ws_size >= need) {
        unsigned short* Xb = (unsigned short*)d_ws;
        unsigned short* Wb = Xb + nX;
        cvt_f32_bf16<<<(int)(nX / 8 / 256), 256, 0, stream>>>(X,  Xb, nX);
        cvt_f32_bf16<<<(int)(nW / 8 / 256), 256, 0, stream>>>(Wt, Wb, nW);
        gemm_bf16<<<grid, 256, 0, stream>>>(Xb, Wb, bias, gnw, gnb, mw, out);
    } else {
        gemm_f32cvt<<<grid, 256, 0, stream>>>(X, Wt, bias, gnw, gnb, mw, out);
    }
}